// Round 1
// baseline (105.929 us; speedup 1.0000x reference)
//
#include <hip/hip_runtime.h>

// iDDPMPrecond: per-sigma preconditioner coefficients.
// out layout (flat, fp32): [0]=c_skip(1.0) | [1..B]=-sigma | [1+B..1+2B]=1/sqrt(s^2+1)
//                          | [1+2B..1+3B]=(M-1-argmin_j|s-u_j|)
// x (d_in[0]) is unused by the reference outputs — deliberately not read.

#define NU_MAX 1024  // u has M+1 = 1001 entries; fits in 4KB LDS

__global__ void __launch_bounds__(256) iddpm_precond_kernel(
    const float* __restrict__ sigma,
    const float* __restrict__ u,
    const int*   __restrict__ Mp,
    float* __restrict__ out,
    int Bn, int nu)
{
    __shared__ float su[NU_MAX];
    // cooperative stage of u into LDS (1001 floats, coalesced)
    for (int j = threadIdx.x; j < nu; j += blockDim.x) su[j] = u[j];
    __syncthreads();

    const int i = blockIdx.x * blockDim.x + threadIdx.x;
    if (i >= Bn) return;

    const float s = sigma[i];

    // Brute-force argmin of |s - u[j]| with strict '<' => first-occurrence
    // tie-break, matching jnp.argmin exactly.
    float best = fabsf(s - su[0]);
    int   bidx = 0;
    #pragma unroll 8
    for (int j = 1; j < nu; ++j) {
        const float d = fabsf(s - su[j]);
        const bool lt = (d < best);
        best = lt ? d : best;
        bidx = lt ? j : bidx;
    }

    const int M = Mp[0];
    if (i == 0) out[0] = 1.0f;                       // c_skip
    out[1 + i]          = -s;                        // c_out
    out[1 + Bn + i]     = 1.0f / sqrtf(s * s + 1.0f);// c_in
    out[1 + 2 * Bn + i] = (float)(M - 1 - bidx);     // c_noise
}

extern "C" void kernel_launch(void* const* d_in, const int* in_sizes, int n_in,
                              void* d_out, int out_size, void* d_ws, size_t ws_size,
                              hipStream_t stream) {
    // inputs (setup_inputs order): x [B*3*8*8] (unused), sigma [B], u [M+1], M [1]
    const float* sigma = (const float*)d_in[1];
    const float* u     = (const float*)d_in[2];
    const int*   Mp    = (const int*)d_in[3];
    float* out = (float*)d_out;

    const int Bn = in_sizes[1];
    const int nu = in_sizes[2];

    const int block = 256;
    const int grid  = (Bn + block - 1) / block;
    iddpm_precond_kernel<<<grid, block, 0, stream>>>(sigma, u, Mp, out, Bn, nu);
}

// Round 2
// 85.220 us; speedup vs baseline: 1.2430x; 1.2430x over previous
//
#include <hip/hip_runtime.h>

// iDDPMPrecond: per-sigma preconditioner coefficients.
// out layout (flat, fp32): [0]=c_skip(1.0) | [1..B]=-sigma | [1+B..1+2B]=1/sqrt(s^2+1)
//                          | [1+2B..1+3B]=(M-1-argmin_j|s-u_j|)
// x (d_in[0]) is unused by the reference outputs — deliberately not read.
//
// u is strictly monotone DECREASING (u[0]~54.7 ... u[M]=0), sigma in [0,1),
// so nearest-value argmin == binary search for the bracketing pair (lo,hi)
// with u[lo] >= s > u[hi], then pick lo iff (u[lo]-s) <= (s-u[hi]).
// Tie (equal distance) -> lo (smaller index) == jnp.argmin first-occurrence.
// Duplicate-value guard (walk back to first equal u) kept for safety even
// though fp32 gaps make duplicates impossible for this schedule.

#define NU_MAX 1024  // u has M+1 = 1001 entries; fits in 4KB LDS

__global__ void __launch_bounds__(256) iddpm_precond_kernel(
    const float* __restrict__ sigma,
    const float* __restrict__ u,
    const int*   __restrict__ Mp,
    float* __restrict__ out,
    int Bn, int nu)
{
    __shared__ float su[NU_MAX];
    for (int j = threadIdx.x; j < nu; j += blockDim.x) su[j] = u[j];
    __syncthreads();

    const int i = blockIdx.x * blockDim.x + threadIdx.x;
    if (i >= Bn) return;

    const float s = sigma[i];

    // Binary search: invariant u[lo] >= s > u[hi] (descending table).
    // s in [0,1): u[0] >> 1 > s and u[nu-1] = 0 <= s, so the bracket is valid.
    int lo = 0, hi = nu - 1;
    while (hi - lo > 1) {
        const int mid = (lo + hi) >> 1;
        const float um = su[mid];
        if (um >= s) lo = mid; else hi = mid;
    }

    const float dlo = su[lo] - s;   // >= 0
    const float dhi = s - su[hi];   // >  0
    int jc = (dlo <= dhi) ? lo : hi;
    // first-occurrence among duplicate u values (defensive; normally untaken)
    while (jc > 0 && su[jc - 1] == su[jc]) --jc;

    const int M = Mp[0];
    if (i == 0) out[0] = 1.0f;                        // c_skip
    out[1 + i]          = -s;                         // c_out
    out[1 + Bn + i]     = 1.0f / sqrtf(s * s + 1.0f); // c_in
    out[1 + 2 * Bn + i] = (float)(M - 1 - jc);        // c_noise
}

extern "C" void kernel_launch(void* const* d_in, const int* in_sizes, int n_in,
                              void* d_out, int out_size, void* d_ws, size_t ws_size,
                              hipStream_t stream) {
    // inputs (setup_inputs order): x [B*3*8*8] (unused), sigma [B], u [M+1], M [1]
    const float* sigma = (const float*)d_in[1];
    const float* u     = (const float*)d_in[2];
    const int*   Mp    = (const int*)d_in[3];
    float* out = (float*)d_out;

    const int Bn = in_sizes[1];
    const int nu = in_sizes[2];

    const int block = 256;
    const int grid  = (Bn + block - 1) / block;
    iddpm_precond_kernel<<<grid, block, 0, stream>>>(sigma, u, Mp, out, Bn, nu);
}